// Round 12
// baseline (182.354 us; speedup 1.0000x reference)
//
#include <hip/hip_runtime.h>
#include <hip/hip_bf16.h>

#define N_ 256
#define D_ 64
#define H_ 4
#define DH_ 32
#define EQKV 384
#define NPOS 65536
#define SCALE_F 0.17677669529663687f
#define BIG_NEG -3.402823466e38f
#define P_STRIDE 264   // bf16 elems; 528 B rows: 16B-aligned, modest 2-4 way banks
#define H_STRIDE 72    // h tile stride (bf16)
#define X_STRIDE 136   // K3 x tile stride (bf16)
#define A_STRIDE 136   // K3 attn tile stride (bf16)
#define O_STRIDE 68    // K3 out staging stride (f32)
#define Q_STRIDE 392   // K1 qkv staging stride (bf16); 784 B rows, 16B-aligned

typedef __attribute__((ext_vector_type(8))) short s16x8;
typedef __attribute__((ext_vector_type(4))) short s16x4;
typedef __attribute__((ext_vector_type(4))) float f32x4;

// ws layout (bytes):
//   qkv     bf16 [65536][384]        @ 0          (50331648 B)
//   bias    f32  [4][i=256][j=256]   @ 50331648   (1048576 B)   [h][i][j], j fastest (coalesced)
//   h       bf16 [65536][64]         @ 51380224   (8388608 B)
//   attn    bf16 [65536][128]        @ 59768832   (16777216 B)

__device__ inline short bfbits(float x) {
    __hip_bfloat16 b = __float2bfloat16(x);
    return *reinterpret_cast<short*>(&b);
}
__device__ inline float b2f(short s) {
    unsigned u = ((unsigned)(unsigned short)s) << 16;
    union { unsigned u; float f; } c; c.u = u; return c.f;
}
__device__ inline s16x8 cvt8(float4 a, float4 b) {
    s16x8 r;
    r[0] = bfbits(a.x); r[1] = bfbits(a.y); r[2] = bfbits(a.z); r[3] = bfbits(a.w);
    r[4] = bfbits(b.x); r[5] = bfbits(b.y); r[6] = bfbits(b.z); r[7] = bfbits(b.w);
    return r;
}

// ---------------- K1: layernorm + qkv + bias (MFMA) — v9 verbatim ----------------
__global__ __launch_bounds__(512) void k1_ln_proj_mfma(
    const float* __restrict__ z, const float* __restrict__ ln_w, const float* __restrict__ ln_b,
    const float* __restrict__ w_qkv, const float* __restrict__ w_bias,
    __hip_bfloat16* __restrict__ qkv_ws, __hip_bfloat16* __restrict__ h_ws,
    float* __restrict__ bias_ws)
{
    __shared__ __align__(16) short smem[64 * Q_STRIDE];
    const int t = threadIdx.x;
    const int wave = t >> 6, lane = t & 63;
    const int pos0 = blockIdx.x * 64;
    const int m = lane & 15, quad = lane >> 4;

    // ---- phase A: layernorm + bias, one row per 8-lane octet ----
    {
        const int oct = lane >> 3;
        const int ocl = lane & 7;
        const int row = wave * 8 + oct;
        const int d0 = ocl * 8;

        const float* zp = z + (size_t)(pos0 + row) * 64 + d0;
        const float4 z0 = *(const float4*)(zp);
        const float4 z1 = *(const float4*)(zp + 4);

        float s  = z0.x + z0.y + z0.z + z0.w + z1.x + z1.y + z1.z + z1.w;
        float s2 = z0.x*z0.x + z0.y*z0.y + z0.z*z0.z + z0.w*z0.w
                 + z1.x*z1.x + z1.y*z1.y + z1.z*z1.z + z1.w*z1.w;
        #pragma unroll
        for (int off = 1; off < 8; off <<= 1) { s += __shfl_xor(s, off); s2 += __shfl_xor(s2, off); }
        const float mu = s * 0.015625f;
        const float var = s2 * 0.015625f - mu * mu;
        const float rs = rsqrtf(var + 1e-5f);

        const float4 lw0 = *(const float4*)(ln_w + d0);
        const float4 lw1 = *(const float4*)(ln_w + d0 + 4);
        const float4 lb0 = *(const float4*)(ln_b + d0);
        const float4 lb1 = *(const float4*)(ln_b + d0 + 4);

        float hv[8];
        hv[0] = (z0.x - mu) * rs * lw0.x + lb0.x;
        hv[1] = (z0.y - mu) * rs * lw0.y + lb0.y;
        hv[2] = (z0.z - mu) * rs * lw0.z + lb0.z;
        hv[3] = (z0.w - mu) * rs * lw0.w + lb0.w;
        hv[4] = (z1.x - mu) * rs * lw1.x + lb1.x;
        hv[5] = (z1.y - mu) * rs * lw1.y + lb1.y;
        hv[6] = (z1.z - mu) * rs * lw1.z + lb1.z;
        hv[7] = (z1.w - mu) * rs * lw1.w + lb1.w;

        s16x8 hb;
        #pragma unroll
        for (int k = 0; k < 8; ++k) hb[k] = bfbits(hv[k]);
        *(s16x8*)(smem + row * H_STRIDE + d0) = hb;

        float bsum[4];
        #pragma unroll
        for (int h4 = 0; h4 < 4; ++h4) {
            const float4 wb0 = *(const float4*)(w_bias + h4 * 64 + d0);
            const float4 wb1 = *(const float4*)(w_bias + h4 * 64 + d0 + 4);
            float b = hv[0]*wb0.x + hv[1]*wb0.y + hv[2]*wb0.z + hv[3]*wb0.w
                    + hv[4]*wb1.x + hv[5]*wb1.y + hv[6]*wb1.z + hv[7]*wb1.w;
            #pragma unroll
            for (int off = 1; off < 8; off <<= 1) b += __shfl_xor(b, off);
            bsum[h4] = b;
        }
        if (ocl == 0) {
            const int gpos = pos0 + row;
            const int gi = gpos >> 8, gj = gpos & 255;
            #pragma unroll
            for (int h4 = 0; h4 < 4; ++h4)
                bias_ws[h4 * NPOS + gi * 256 + gj] = bsum[h4];   // [h][i][j]
        }
    }
    __syncthreads();

    // ---- phase B0: cooperative coalesced h store (16 B/thread) ----
    {
        const int row = t >> 3, c8 = (t & 7) * 8;
        *(s16x8*)(h_ws + (size_t)(pos0 + row) * 64 + c8) =
            *(const s16x8*)(smem + row * H_STRIDE + c8);
    }

    // ---- phase B: fragments + MFMA (SWAPPED: A=W cols, B=h rows). 8 waves x 48 cols ----
    const int colbase = wave * 48;
    s16x8 wfrag[3][2];
    #pragma unroll
    for (int ct = 0; ct < 3; ++ct) {
        const int col = colbase + ct * 16 + m;
        const float* wp = w_qkv + (size_t)col * 64;
        #pragma unroll
        for (int kt = 0; kt < 2; ++kt) {
            const float4 w0 = *(const float4*)(wp + kt * 32 + quad * 8);
            const float4 w1 = *(const float4*)(wp + kt * 32 + quad * 8 + 4);
            wfrag[ct][kt] = cvt8(w0, w1);
        }
    }

    s16x8 hfrag[4][2];
    #pragma unroll
    for (int pt = 0; pt < 4; ++pt)
        #pragma unroll
        for (int kt = 0; kt < 2; ++kt)
            hfrag[pt][kt] = *(const s16x8*)(smem + (pt * 16 + m) * H_STRIDE + kt * 32 + quad * 8);

    f32x4 acc[3][4];
    #pragma unroll
    for (int ct = 0; ct < 3; ++ct)
        #pragma unroll
        for (int pt = 0; pt < 4; ++pt)
            acc[ct][pt] = (f32x4){0.f, 0.f, 0.f, 0.f};

    #pragma unroll
    for (int kt = 0; kt < 2; ++kt)
        #pragma unroll
        for (int ct = 0; ct < 3; ++ct)
            #pragma unroll
            for (int pt = 0; pt < 4; ++pt)
                acc[ct][pt] = __builtin_amdgcn_mfma_f32_16x16x32_bf16(
                    wfrag[ct][kt], hfrag[pt][kt], acc[ct][pt], 0, 0, 0);

    __syncthreads();

    // ---- phase C: accumulators -> bf16 LDS staging tile [64][Q_STRIDE], packed b64 writes ----
    #pragma unroll
    for (int ct = 0; ct < 3; ++ct)
        #pragma unroll
        for (int pt = 0; pt < 4; ++pt) {
            s16x4 pk;
            pk[0] = bfbits(acc[ct][pt][0]); pk[1] = bfbits(acc[ct][pt][1]);
            pk[2] = bfbits(acc[ct][pt][2]); pk[3] = bfbits(acc[ct][pt][3]);
            *(s16x4*)(smem + (pt * 16 + m) * Q_STRIDE + colbase + ct * 16 + quad * 4) = pk;
        }
    __syncthreads();

    // ---- phase D: cooperative coalesced qkv store, 16 B/lane ----
    #pragma unroll
    for (int i = 0; i < 6; ++i) {
        const int idx = i * 512 + t;
        const int row = idx / 48, c8 = (idx % 48) * 8;
        *(s16x8*)(qkv_ws + (size_t)(pos0 + row) * EQKV + c8) =
            *(const s16x8*)(smem + row * Q_STRIDE + c8);
    }
}

// ---------------- K2: MFMA attention, block = (n,h) — v12: swapped-S phase 2 ----------------
// s = mfma(kf, qf) puts reg r on 4 consecutive j at lane-owned row i = mt*16+m:
// P writes 32 scalar b16 -> 8 packed b64; row-sum 16 shfl -> 2; bias 32 scalar -> 8 float4.
// p_s memory layout, PV phase, and all numerics-relevant values unchanged.
__global__ __launch_bounds__(512, 4) void k2_attn_mfma(
    const __hip_bfloat16* __restrict__ qkv_ws, const float* __restrict__ bias_ws,
    const int* __restrict__ mask, __hip_bfloat16* __restrict__ attn_bf)
{
    __shared__ __align__(16) short p_s[64 * P_STRIDE];
    __shared__ __align__(16) short vt_s[32 * P_STRIDE];
    __shared__ __align__(16) float keep[256];
    __shared__ float redl[64][2];

    const int bx = blockIdx.x;
    const int n = bx & 255, h = bx >> 8;
    const int t = threadIdx.x;
    const int wave = t >> 6, lane = t & 63;
    const int m = lane & 15, quad = lane >> 4;
    const int mt = wave & 3, nh = wave >> 2;

    if (t < 256) keep[t] = (mask[n * 256 + t] != 0) ? 1.0f : 0.0f;

    // stage V^T once
    {
        const int j = t >> 1, dh = (t & 1) * 16;
        const __hip_bfloat16* vp = qkv_ws + (size_t)(n * 256 + j) * 384 + 256 + h * 32 + dh;
        s16x8 v0 = *(const s16x8*)vp;
        s16x8 v1 = *(const s16x8*)(vp + 8);
        #pragma unroll
        for (int e = 0; e < 8; ++e) {
            vt_s[(dh + e) * P_STRIDE + j]     = v0[e];
            vt_s[(dh + 8 + e) * P_STRIDE + j] = v1[e];
        }
    }

    // K fragments loaded once, held in registers across all 4 i-groups
    s16x8 kf[8];
    #pragma unroll
    for (int tt = 0; tt < 8; ++tt) {
        const int jt = nh * 8 + tt;
        kf[tt] = *(const s16x8*)(qkv_ws + (size_t)(n * 256 + jt * 16 + m) * 384 + 128 + h * 32 + quad * 8);
    }

    // prefetch ig0: Q fragment + 8 float4 bias rows (lane row i = mt*16+m, cols nh*128+tt*16+quad*4)
    const float* bias_h = bias_ws + (size_t)h * NPOS;
    const int irow_l = mt * 16 + m;                 // lane-owned i row (local)
    const int jq = nh * 128 + quad * 4;             // + tt*16
    s16x8 qf = *(const s16x8*)(qkv_ws + (size_t)(n * 256 + irow_l) * 384 + h * 32 + quad * 8);
    float4 bb[8];
    #pragma unroll
    for (int tt = 0; tt < 8; ++tt)
        bb[tt] = *(const float4*)(bias_h + (size_t)irow_l * 256 + jq + tt * 16);

    __syncthreads();

    for (int ig = 0; ig < 4; ++ig) {
        const int i0 = ig * 64;

        // ---- phase 1: S^T-view = mfma(K, Q): lane holds row i = i0+irow_l, cols jq+tt*16+r ----
        f32x4 s[8];
        #pragma unroll
        for (int tt = 0; tt < 8; ++tt) {
            f32x4 z4 = {0.f, 0.f, 0.f, 0.f};
            s[tt] = __builtin_amdgcn_mfma_f32_16x16x32_bf16(kf[tt], qf, z4, 0, 0, 0);
        }
        #pragma unroll
        for (int tt = 0; tt < 8; ++tt) {
            const float4 kp4 = *(const float4*)(keep + jq + tt * 16);
            const float* kp = reinterpret_cast<const float*>(&kp4);
            const float* bp = reinterpret_cast<const float*>(&bb[tt]);
            #pragma unroll
            for (int r = 0; r < 4; ++r) {
                const float sv = s[tt][r] * SCALE_F + bp[r];
                s[tt][r] = (kp[r] != 0.f) ? sv : BIG_NEG;
            }
        }

        // ---- phase 2: exp, lane-local row sum (+2 shfl), packed P writes ----
        {
            float lsum = 0.f;
            #pragma unroll
            for (int tt = 0; tt < 8; ++tt)
                #pragma unroll
                for (int r = 0; r < 4; ++r) {
                    const float p = __expf(s[tt][r]);   // masked -> exp(BIG_NEG) = 0
                    s[tt][r] = p;
                    lsum += p;
                }
            lsum += __shfl_xor(lsum, 16);
            lsum += __shfl_xor(lsum, 32);
            if (lane < 16) redl[mt * 16 + lane][nh] = lsum;
            #pragma unroll
            for (int tt = 0; tt < 8; ++tt) {
                s16x4 pk;
                pk[0] = bfbits(s[tt][0]); pk[1] = bfbits(s[tt][1]);
                pk[2] = bfbits(s[tt][2]); pk[3] = bfbits(s[tt][3]);
                *(s16x4*)(p_s + irow_l * P_STRIDE + jq + tt * 16) = pk;
            }
        }

        // ---- prefetch next i-group (Q frag + bias): latency hides under barrier + PV ----
        if (ig < 3) {
            const int i0n = i0 + 64;
            qf = *(const s16x8*)(qkv_ws + (size_t)(n * 256 + i0n + irow_l) * 384 + h * 32 + quad * 8);
            #pragma unroll
            for (int tt = 0; tt < 8; ++tt)
                bb[tt] = *(const float4*)(bias_h + (size_t)(i0n + irow_l) * 256 + jq + tt * 16);
        }
        __syncthreads();

        // ---- phase 3: O = P V (dual accumulator chains), scale 1/l, store bf16 ----
        {
            f32x4 o0 = {0.f, 0.f, 0.f, 0.f};
            f32x4 o1 = {0.f, 0.f, 0.f, 0.f};
            const int arow = mt * 16 + m;
            const int brow = nh * 16 + m;
            #pragma unroll
            for (int kt = 0; kt < 4; ++kt) {
                const s16x8 ap0 = *(const s16x8*)(p_s + arow * P_STRIDE + (2 * kt) * 32 + quad * 8);
                const s16x8 bv0 = *(const s16x8*)(vt_s + brow * P_STRIDE + (2 * kt) * 32 + quad * 8);
                o0 = __builtin_amdgcn_mfma_f32_16x16x32_bf16(ap0, bv0, o0, 0, 0, 0);
                const s16x8 ap1 = *(const s16x8*)(p_s + arow * P_STRIDE + (2 * kt + 1) * 32 + quad * 8);
                const s16x8 bv1 = *(const s16x8*)(vt_s + brow * P_STRIDE + (2 * kt + 1) * 32 + quad * 8);
                o1 = __builtin_amdgcn_mfma_f32_16x16x32_bf16(ap1, bv1, o1, 0, 0, 0);
            }
            #pragma unroll
            for (int r = 0; r < 4; ++r) {
                const int row = mt * 16 + quad * 4 + r;
                const float l = fmaxf(redl[row][0] + redl[row][1], 1e-30f);
                const float val = (o0[r] + o1[r]) * (1.0f / l);
                const int ig_row = i0 + row;
                attn_bf[(size_t)(n * 256 + ig_row) * 128 + h * 32 + nh * 16 + m] = __float2bfloat16(val);
            }
        }
        if (ig < 3) __syncthreads();   // protect p_s / redl for next i-group (elide dead last barrier)
    }
}

// ---------------- K3: gate = sigmoid(h @ w_gate^T) via MFMA; out = (attn*gate) @ w_out^T (R9 verbatim) ----------------
__global__ __launch_bounds__(512) void k3_proj_mfma(
    const __hip_bfloat16* __restrict__ attn_bf, const __hip_bfloat16* __restrict__ h_ws,
    const float* __restrict__ w_gate, const float* __restrict__ w_out, float* __restrict__ out)
{
    __shared__ __align__(16) short h_s[64 * H_STRIDE];
    __shared__ __align__(16) short a_s[64 * A_STRIDE];
    __shared__ __align__(16) short x_s[64 * X_STRIDE];
    const int t = threadIdx.x;
    const int wave = t >> 6, lane = t & 63;
    const int pos0 = blockIdx.x * 64;
    const int m = lane & 15, quad = lane >> 4;

    {
        const int row = t >> 3, c8 = (t & 7) * 8;
        *(s16x8*)(h_s + row * H_STRIDE + c8) =
            *(const s16x8*)(h_ws + (size_t)(pos0 + row) * 64 + c8);
    }
    #pragma unroll
    for (int i = 0; i < 2; ++i) {
        const int idx = i * 512 + t;
        const int row = idx >> 4, c8 = (idx & 15) * 8;
        *(s16x8*)(a_s + row * A_STRIDE + c8) =
            *(const s16x8*)(attn_bf + (size_t)(pos0 + row) * 128 + c8);
    }
    __syncthreads();

    {
        const int mt = wave & 3, cg = wave >> 2;
        s16x8 ha[2];
        #pragma unroll
        for (int kt = 0; kt < 2; ++kt)
            ha[kt] = *(const s16x8*)(h_s + (mt * 16 + m) * H_STRIDE + kt * 32 + quad * 8);
        #pragma unroll
        for (int nt = 0; nt < 4; ++nt) {
            const float* wp = w_gate + (size_t)(cg * 64 + nt * 16 + m) * 64;
            const s16x8 b0 = cvt8(*(const float4*)(wp + quad * 8),
                                  *(const float4*)(wp + quad * 8 + 4));
            const s16x8 b1 = cvt8(*(const float4*)(wp + 32 + quad * 8),
                                  *(const float4*)(wp + 32 + quad * 8 + 4));
            f32x4 g4 = (f32x4){0.f, 0.f, 0.f, 0.f};
            g4 = __builtin_amdgcn_mfma_f32_16x16x32_bf16(ha[0], b0, g4, 0, 0, 0);
            g4 = __builtin_amdgcn_mfma_f32_16x16x32_bf16(ha[1], b1, g4, 0, 0, 0);
            const int col = cg * 64 + nt * 16 + m;
            #pragma unroll
            for (int r = 0; r < 4; ++r) {
                const int row = mt * 16 + quad * 4 + r;
                const float gv = 1.0f / (1.0f + __expf(-g4[r]));
                x_s[row * X_STRIDE + col] = bfbits(b2f(a_s[row * A_STRIDE + col]) * gv);
            }
        }
    }
    __syncthreads();

    const int mt = wave & 3, nh = wave >> 2;
    s16x8 bfrag[2][4];
    #pragma unroll
    for (int nt = 0; nt < 2; ++nt) {
        const int d = nh * 32 + nt * 16 + m;
        const float* wp = w_out + (size_t)d * 128;
        #pragma unroll
        for (int kt = 0; kt < 4; ++kt) {
            const float4 w0 = *(const float4*)(wp + kt * 32 + quad * 8);
            const float4 w1 = *(const float4*)(wp + kt * 32 + quad * 8 + 4);
            bfrag[nt][kt] = cvt8(w0, w1);
        }
    }

    s16x8 afrag[4];
    #pragma unroll
    for (int kt = 0; kt < 4; ++kt)
        afrag[kt] = *(const s16x8*)(x_s + (mt * 16 + m) * X_STRIDE + kt * 32 + quad * 8);

    f32x4 acc[2];
    acc[0] = (f32x4){0.f, 0.f, 0.f, 0.f};
    acc[1] = (f32x4){0.f, 0.f, 0.f, 0.f};
    #pragma unroll
    for (int kt = 0; kt < 4; ++kt) {
        acc[0] = __builtin_amdgcn_mfma_f32_16x16x32_bf16(afrag[kt], bfrag[0][kt], acc[0], 0, 0, 0);
        acc[1] = __builtin_amdgcn_mfma_f32_16x16x32_bf16(afrag[kt], bfrag[1][kt], acc[1], 0, 0, 0);
    }

    float* o_s = (float*)a_s;
    #pragma unroll
    for (int nt = 0; nt < 2; ++nt) {
        const int d = nh * 32 + nt * 16 + m;
        #pragma unroll
        for (int r = 0; r < 4; ++r) {
            const int row = mt * 16 + quad * 4 + r;
            o_s[row * O_STRIDE + d] = acc[nt][r];
        }
    }
    __syncthreads();

    #pragma unroll
    for (int i = 0; i < 2; ++i) {
        const int idx = i * 512 + t;
        const int row = idx >> 4, c4 = (idx & 15) * 4;
        *(float4*)(out + (size_t)(pos0 + row) * 64 + c4) =
            *(const float4*)(o_s + row * O_STRIDE + c4);
    }
}

extern "C" void kernel_launch(void* const* d_in, const int* in_sizes, int n_in,
                              void* d_out, int out_size, void* d_ws, size_t ws_size,
                              hipStream_t stream) {
    const float* z      = (const float*)d_in[0];
    const int*   mask   = (const int*)d_in[1];
    const float* ln_w   = (const float*)d_in[2];
    const float* ln_b   = (const float*)d_in[3];
    const float* w_qkv  = (const float*)d_in[4];
    const float* w_bias = (const float*)d_in[5];
    const float* w_out  = (const float*)d_in[6];
    const float* w_gate = (const float*)d_in[7];
    float* out = (float*)d_out;

    char* ws = (char*)d_ws;
    __hip_bfloat16* qkv_ws  = (__hip_bfloat16*)(ws);
    float*          bias_ws = (float*)(ws + 50331648);
    __hip_bfloat16* h_ws    = (__hip_bfloat16*)(ws + 51380224);
    __hip_bfloat16* attn_bf = (__hip_bfloat16*)(ws + 59768832);

    k1_ln_proj_mfma<<<1024, 512, 0, stream>>>(z, ln_w, ln_b, w_qkv, w_bias,
                                              qkv_ws, h_ws, bias_ws);
    k2_attn_mfma<<<1024, 512, 0, stream>>>(qkv_ws, bias_ws, mask, attn_bf);
    k3_proj_mfma<<<1024, 512, 0, stream>>>(attn_bf, h_ws, w_gate, w_out, out);
}

// Round 13
// 175.543 us; speedup vs baseline: 1.0388x; 1.0388x over previous
//
#include <hip/hip_runtime.h>
#include <hip/hip_bf16.h>

#define N_ 256
#define D_ 64
#define H_ 4
#define DH_ 32
#define EQKV 384
#define NPOS 65536
#define SCALE_F 0.17677669529663687f
#define BIG_NEG -3.402823466e38f
#define P_STRIDE 264   // bf16 elems; 528 B rows: 16B-aligned, modest 2-4 way banks
#define H_STRIDE 72    // h tile stride (bf16)
#define X_STRIDE 136   // K3 x tile stride (bf16)
#define A_STRIDE 136   // K3 attn tile stride (bf16)
#define O_STRIDE 68    // K3 out staging stride (f32)
#define Q_STRIDE 392   // K1 qkv staging stride (bf16); 784 B rows, 16B-aligned

typedef __attribute__((ext_vector_type(8))) short s16x8;
typedef __attribute__((ext_vector_type(4))) short s16x4;
typedef __attribute__((ext_vector_type(4))) float f32x4;

// ws layout (bytes):
//   qkv     bf16 [65536][384]        @ 0          (50331648 B)
//   bias    f32  [4][i=256][j=256]   @ 50331648   (1048576 B)   [h][i][j], j fastest (coalesced)
//   h       bf16 [65536][64]        @ 51380224   (8388608 B)
//   attn    bf16 [65536][128]        @ 59768832   (16777216 B)

__device__ inline short bfbits(float x) {
    __hip_bfloat16 b = __float2bfloat16(x);
    return *reinterpret_cast<short*>(&b);
}
__device__ inline float b2f(short s) {
    unsigned u = ((unsigned)(unsigned short)s) << 16;
    union { unsigned u; float f; } c; c.u = u; return c.f;
}
__device__ inline s16x8 cvt8(float4 a, float4 b) {
    s16x8 r;
    r[0] = bfbits(a.x); r[1] = bfbits(a.y); r[2] = bfbits(a.z); r[3] = bfbits(a.w);
    r[4] = bfbits(b.x); r[5] = bfbits(b.y); r[6] = bfbits(b.z); r[7] = bfbits(b.w);
    return r;
}

// ---------------- K1: layernorm + qkv + bias (MFMA) — v9 verbatim ----------------
__global__ __launch_bounds__(512) void k1_ln_proj_mfma(
    const float* __restrict__ z, const float* __restrict__ ln_w, const float* __restrict__ ln_b,
    const float* __restrict__ w_qkv, const float* __restrict__ w_bias,
    __hip_bfloat16* __restrict__ qkv_ws, __hip_bfloat16* __restrict__ h_ws,
    float* __restrict__ bias_ws)
{
    __shared__ __align__(16) short smem[64 * Q_STRIDE];
    const int t = threadIdx.x;
    const int wave = t >> 6, lane = t & 63;
    const int pos0 = blockIdx.x * 64;
    const int m = lane & 15, quad = lane >> 4;

    // ---- phase A: layernorm + bias, one row per 8-lane octet ----
    {
        const int oct = lane >> 3;
        const int ocl = lane & 7;
        const int row = wave * 8 + oct;
        const int d0 = ocl * 8;

        const float* zp = z + (size_t)(pos0 + row) * 64 + d0;
        const float4 z0 = *(const float4*)(zp);
        const float4 z1 = *(const float4*)(zp + 4);

        float s  = z0.x + z0.y + z0.z + z0.w + z1.x + z1.y + z1.z + z1.w;
        float s2 = z0.x*z0.x + z0.y*z0.y + z0.z*z0.z + z0.w*z0.w
                 + z1.x*z1.x + z1.y*z1.y + z1.z*z1.z + z1.w*z1.w;
        #pragma unroll
        for (int off = 1; off < 8; off <<= 1) { s += __shfl_xor(s, off); s2 += __shfl_xor(s2, off); }
        const float mu = s * 0.015625f;
        const float var = s2 * 0.015625f - mu * mu;
        const float rs = rsqrtf(var + 1e-5f);

        const float4 lw0 = *(const float4*)(ln_w + d0);
        const float4 lw1 = *(const float4*)(ln_w + d0 + 4);
        const float4 lb0 = *(const float4*)(ln_b + d0);
        const float4 lb1 = *(const float4*)(ln_b + d0 + 4);

        float hv[8];
        hv[0] = (z0.x - mu) * rs * lw0.x + lb0.x;
        hv[1] = (z0.y - mu) * rs * lw0.y + lb0.y;
        hv[2] = (z0.z - mu) * rs * lw0.z + lb0.z;
        hv[3] = (z0.w - mu) * rs * lw0.w + lb0.w;
        hv[4] = (z1.x - mu) * rs * lw1.x + lb1.x;
        hv[5] = (z1.y - mu) * rs * lw1.y + lb1.y;
        hv[6] = (z1.z - mu) * rs * lw1.z + lb1.z;
        hv[7] = (z1.w - mu) * rs * lw1.w + lb1.w;

        s16x8 hb;
        #pragma unroll
        for (int k = 0; k < 8; ++k) hb[k] = bfbits(hv[k]);
        *(s16x8*)(smem + row * H_STRIDE + d0) = hb;

        float bsum[4];
        #pragma unroll
        for (int h4 = 0; h4 < 4; ++h4) {
            const float4 wb0 = *(const float4*)(w_bias + h4 * 64 + d0);
            const float4 wb1 = *(const float4*)(w_bias + h4 * 64 + d0 + 4);
            float b = hv[0]*wb0.x + hv[1]*wb0.y + hv[2]*wb0.z + hv[3]*wb0.w
                    + hv[4]*wb1.x + hv[5]*wb1.y + hv[6]*wb1.z + hv[7]*wb1.w;
            #pragma unroll
            for (int off = 1; off < 8; off <<= 1) b += __shfl_xor(b, off);
            bsum[h4] = b;
        }
        if (ocl == 0) {
            const int gpos = pos0 + row;
            const int gi = gpos >> 8, gj = gpos & 255;
            #pragma unroll
            for (int h4 = 0; h4 < 4; ++h4)
                bias_ws[h4 * NPOS + gi * 256 + gj] = bsum[h4];   // [h][i][j]
        }
    }
    __syncthreads();

    // ---- phase B0: cooperative coalesced h store (16 B/thread) ----
    {
        const int row = t >> 3, c8 = (t & 7) * 8;
        *(s16x8*)(h_ws + (size_t)(pos0 + row) * 64 + c8) =
            *(const s16x8*)(smem + row * H_STRIDE + c8);
    }

    // ---- phase B: fragments + MFMA (SWAPPED: A=W cols, B=h rows). 8 waves x 48 cols ----
    const int colbase = wave * 48;
    s16x8 wfrag[3][2];
    #pragma unroll
    for (int ct = 0; ct < 3; ++ct) {
        const int col = colbase + ct * 16 + m;
        const float* wp = w_qkv + (size_t)col * 64;
        #pragma unroll
        for (int kt = 0; kt < 2; ++kt) {
            const float4 w0 = *(const float4*)(wp + kt * 32 + quad * 8);
            const float4 w1 = *(const float4*)(wp + kt * 32 + quad * 8 + 4);
            wfrag[ct][kt] = cvt8(w0, w1);
        }
    }

    s16x8 hfrag[4][2];
    #pragma unroll
    for (int pt = 0; pt < 4; ++pt)
        #pragma unroll
        for (int kt = 0; kt < 2; ++kt)
            hfrag[pt][kt] = *(const s16x8*)(smem + (pt * 16 + m) * H_STRIDE + kt * 32 + quad * 8);

    f32x4 acc[3][4];
    #pragma unroll
    for (int ct = 0; ct < 3; ++ct)
        #pragma unroll
        for (int pt = 0; pt < 4; ++pt)
            acc[ct][pt] = (f32x4){0.f, 0.f, 0.f, 0.f};

    #pragma unroll
    for (int kt = 0; kt < 2; ++kt)
        #pragma unroll
        for (int ct = 0; ct < 3; ++ct)
            #pragma unroll
            for (int pt = 0; pt < 4; ++pt)
                acc[ct][pt] = __builtin_amdgcn_mfma_f32_16x16x32_bf16(
                    wfrag[ct][kt], hfrag[pt][kt], acc[ct][pt], 0, 0, 0);

    __syncthreads();

    // ---- phase C: accumulators -> bf16 LDS staging tile [64][Q_STRIDE], packed b64 writes ----
    #pragma unroll
    for (int ct = 0; ct < 3; ++ct)
        #pragma unroll
        for (int pt = 0; pt < 4; ++pt) {
            s16x4 pk;
            pk[0] = bfbits(acc[ct][pt][0]); pk[1] = bfbits(acc[ct][pt][1]);
            pk[2] = bfbits(acc[ct][pt][2]); pk[3] = bfbits(acc[ct][pt][3]);
            *(s16x4*)(smem + (pt * 16 + m) * Q_STRIDE + colbase + ct * 16 + quad * 4) = pk;
        }
    __syncthreads();

    // ---- phase D: cooperative coalesced qkv store, 16 B/lane ----
    #pragma unroll
    for (int i = 0; i < 6; ++i) {
        const int idx = i * 512 + t;
        const int row = idx / 48, c8 = (idx % 48) * 8;
        *(s16x8*)(qkv_ws + (size_t)(pos0 + row) * EQKV + c8) =
            *(const s16x8*)(smem + row * Q_STRIDE + c8);
    }
}

// ---------------- K2: MFMA attention, block = (n,h), 4 i-groups looped (R3/R9 verbatim; dead last barrier elided) ----------------
__global__ __launch_bounds__(512, 4) void k2_attn_mfma(
    const __hip_bfloat16* __restrict__ qkv_ws, const float* __restrict__ bias_ws,
    const int* __restrict__ mask, __hip_bfloat16* __restrict__ attn_bf)
{
    __shared__ __align__(16) short p_s[64 * P_STRIDE];
    __shared__ __align__(16) short vt_s[32 * P_STRIDE];
    __shared__ float keep[256];
    __shared__ float redl[64][2];

    const int bx = blockIdx.x;
    const int n = bx & 255, h = bx >> 8;
    const int t = threadIdx.x;
    const int wave = t >> 6, lane = t & 63;
    const int m = lane & 15, quad = lane >> 4;
    const int mt = wave & 3, nh = wave >> 2;

    if (t < 256) keep[t] = (mask[n * 256 + t] != 0) ? 1.0f : 0.0f;

    // stage V^T once
    {
        const int j = t >> 1, dh = (t & 1) * 16;
        const __hip_bfloat16* vp = qkv_ws + (size_t)(n * 256 + j) * 384 + 256 + h * 32 + dh;
        s16x8 v0 = *(const s16x8*)vp;
        s16x8 v1 = *(const s16x8*)(vp + 8);
        #pragma unroll
        for (int e = 0; e < 8; ++e) {
            vt_s[(dh + e) * P_STRIDE + j]     = v0[e];
            vt_s[(dh + 8 + e) * P_STRIDE + j] = v1[e];
        }
    }

    // K fragments loaded once, held in registers across all 4 i-groups
    s16x8 kf[8];
    #pragma unroll
    for (int tt = 0; tt < 8; ++tt) {
        const int jt = nh * 8 + tt;
        kf[tt] = *(const s16x8*)(qkv_ws + (size_t)(n * 256 + jt * 16 + m) * 384 + 128 + h * 32 + quad * 8);
    }

    // prefetch ig0: Q fragment + all 32 bias scalars (coalesced across lanes: j = tile*16 + m)
    const int jcol0 = nh * 128 + m;            // + tt*16
    const float* bias_h = bias_ws + (size_t)h * NPOS;
    s16x8 qf = *(const s16x8*)(qkv_ws + (size_t)(n * 256 + mt * 16 + m) * 384 + h * 32 + quad * 8);
    float bb[8][4];
    #pragma unroll
    for (int tt = 0; tt < 8; ++tt)
        #pragma unroll
        for (int r = 0; r < 4; ++r)
            bb[tt][r] = bias_h[(mt * 16 + quad * 4 + r) * 256 + jcol0 + tt * 16];

    __syncthreads();

    for (int ig = 0; ig < 4; ++ig) {
        const int i0 = ig * 64;

        // ---- phase 1: S = Q K^T (prefetched Q), fuse scale + bias (prefetched regs) + mask ----
        f32x4 s[8];
        #pragma unroll
        for (int tt = 0; tt < 8; ++tt) {
            f32x4 z4 = {0.f, 0.f, 0.f, 0.f};
            s[tt] = __builtin_amdgcn_mfma_f32_16x16x32_bf16(qf, kf[tt], z4, 0, 0, 0);
        }
        #pragma unroll
        for (int tt = 0; tt < 8; ++tt) {
            const float kp = keep[jcol0 + tt * 16];
            #pragma unroll
            for (int r = 0; r < 4; ++r) {
                const float sv = s[tt][r] * SCALE_F + bb[tt][r];
                s[tt][r] = (kp != 0.f) ? sv : BIG_NEG;
            }
        }

        // ---- phase 2: exp (no max-sub: |S| bounded by construction), row sums, P to LDS ----
        {
            float ls[4];
            #pragma unroll
            for (int r = 0; r < 4; ++r) {
                float acc = 0.f;
                #pragma unroll
                for (int tt = 0; tt < 8; ++tt) {
                    const float p = __expf(s[tt][r]);   // masked -> exp(BIG_NEG) = 0
                    s[tt][r] = p;
                    acc += p;
                }
                #pragma unroll
                for (int off = 1; off < 16; off <<= 1) acc += __shfl_xor(acc, off);
                ls[r] = acc;
            }
            if (m == 0) {
                #pragma unroll
                for (int r = 0; r < 4; ++r) redl[mt * 16 + quad * 4 + r][nh] = ls[r];
            }
            #pragma unroll
            for (int tt = 0; tt < 8; ++tt) {
                const int col = (nh * 8 + tt) * 16 + m;
                #pragma unroll
                for (int r = 0; r < 4; ++r) {
                    const int row = mt * 16 + quad * 4 + r;
                    p_s[row * P_STRIDE + col] = bfbits(s[tt][r]);
                }
            }
        }

        // ---- prefetch next i-group (Q frag + bias): latency hides under barrier + PV ----
        if (ig < 3) {
            const int i0n = i0 + 64;
            qf = *(const s16x8*)(qkv_ws + (size_t)(n * 256 + i0n + mt * 16 + m) * 384 + h * 32 + quad * 8);
            #pragma unroll
            for (int tt = 0; tt < 8; ++tt)
                #pragma unroll
                for (int r = 0; r < 4; ++r)
                    bb[tt][r] = bias_h[(i0n + mt * 16 + quad * 4 + r) * 256 + jcol0 + tt * 16];
        }
        __syncthreads();

        // ---- phase 3: O = P V (dual accumulator chains), scale 1/l, store bf16 ----
        {
            f32x4 o0 = {0.f, 0.f, 0.f, 0.f};
            f32x4 o1 = {0.f, 0.f, 0.f, 0.f};
            const int arow = mt * 16 + m;
            const int brow = nh * 16 + m;
            #pragma unroll
            for (int kt = 0; kt < 4; ++kt) {
                const s16x8 ap0 = *(const s16x8*)(p_s + arow * P_STRIDE + (2 * kt) * 32 + quad * 8);
                const s16x8 bv0 = *(const s16x8*)(vt_s + brow * P_STRIDE + (2 * kt) * 32 + quad * 8);
                o0 = __builtin_amdgcn_mfma_f32_16x16x32_bf16(ap0, bv0, o0, 0, 0, 0);
                const s16x8 ap1 = *(const s16x8*)(p_s + arow * P_STRIDE + (2 * kt + 1) * 32 + quad * 8);
                const s16x8 bv1 = *(const s16x8*)(vt_s + brow * P_STRIDE + (2 * kt + 1) * 32 + quad * 8);
                o1 = __builtin_amdgcn_mfma_f32_16x16x32_bf16(ap1, bv1, o1, 0, 0, 0);
            }
            #pragma unroll
            for (int r = 0; r < 4; ++r) {
                const int row = mt * 16 + quad * 4 + r;
                const float l = fmaxf(redl[row][0] + redl[row][1], 1e-30f);
                const float val = (o0[r] + o1[r]) * (1.0f / l);
                const int ig_row = i0 + row;
                attn_bf[(size_t)(n * 256 + ig_row) * 128 + h * 32 + nh * 16 + m] = __float2bfloat16(val);
            }
        }
        if (ig < 3) __syncthreads();   // protect p_s / redl for next i-group (last one is dead)
    }
}

// ---------------- K3: gate = sigmoid(h @ w_gate^T) via MFMA; out = (attn*gate) @ w_out^T (R9 verbatim) ----------------
__global__ __launch_bounds__(512) void k3_proj_mfma(
    const __hip_bfloat16* __restrict__ attn_bf, const __hip_bfloat16* __restrict__ h_ws,
    const float* __restrict__ w_gate, const float* __restrict__ w_out, float* __restrict__ out)
{
    __shared__ __align__(16) short h_s[64 * H_STRIDE];
    __shared__ __align__(16) short a_s[64 * A_STRIDE];
    __shared__ __align__(16) short x_s[64 * X_STRIDE];
    const int t = threadIdx.x;
    const int wave = t >> 6, lane = t & 63;
    const int pos0 = blockIdx.x * 64;
    const int m = lane & 15, quad = lane >> 4;

    {
        const int row = t >> 3, c8 = (t & 7) * 8;
        *(s16x8*)(h_s + row * H_STRIDE + c8) =
            *(const s16x8*)(h_ws + (size_t)(pos0 + row) * 64 + c8);
    }
    #pragma unroll
    for (int i = 0; i < 2; ++i) {
        const int idx = i * 512 + t;
        const int row = idx >> 4, c8 = (idx & 15) * 8;
        *(s16x8*)(a_s + row * A_STRIDE + c8) =
            *(const s16x8*)(attn_bf + (size_t)(pos0 + row) * 128 + c8);
    }
    __syncthreads();

    {
        const int mt = wave & 3, cg = wave >> 2;
        s16x8 ha[2];
        #pragma unroll
        for (int kt = 0; kt < 2; ++kt)
            ha[kt] = *(const s16x8*)(h_s + (mt * 16 + m) * H_STRIDE + kt * 32 + quad * 8);
        #pragma unroll
        for (int nt = 0; nt < 4; ++nt) {
            const float* wp = w_gate + (size_t)(cg * 64 + nt * 16 + m) * 64;
            const s16x8 b0 = cvt8(*(const float4*)(wp + quad * 8),
                                  *(const float4*)(wp + quad * 8 + 4));
            const s16x8 b1 = cvt8(*(const float4*)(wp + 32 + quad * 8),
                                  *(const float4*)(wp + 32 + quad * 8 + 4));
            f32x4 g4 = (f32x4){0.f, 0.f, 0.f, 0.f};
            g4 = __builtin_amdgcn_mfma_f32_16x16x32_bf16(ha[0], b0, g4, 0, 0, 0);
            g4 = __builtin_amdgcn_mfma_f32_16x16x32_bf16(ha[1], b1, g4, 0, 0, 0);
            const int col = cg * 64 + nt * 16 + m;
            #pragma unroll
            for (int r = 0; r < 4; ++r) {
                const int row = mt * 16 + quad * 4 + r;
                const float gv = 1.0f / (1.0f + __expf(-g4[r]));
                x_s[row * X_STRIDE + col] = bfbits(b2f(a_s[row * A_STRIDE + col]) * gv);
            }
        }
    }
    __syncthreads();

    const int mt = wave & 3, nh = wave >> 2;
    s16x8 bfrag[2][4];
    #pragma unroll
    for (int nt = 0; nt < 2; ++nt) {
        const int d = nh * 32 + nt * 16 + m;
        const float* wp = w_out + (size_t)d * 128;
        #pragma unroll
        for (int kt = 0; kt < 4; ++kt) {
            const float4 w0 = *(const float4*)(wp + kt * 32 + quad * 8);
            const float4 w1 = *(const float4*)(wp + kt * 32 + quad * 8 + 4);
            bfrag[nt][kt] = cvt8(w0, w1);
        }
    }

    s16x8 afrag[4];
    #pragma unroll
    for (int kt = 0; kt < 4; ++kt)
        afrag[kt] = *(const s16x8*)(x_s + (mt * 16 + m) * X_STRIDE + kt * 32 + quad * 8);

    f32x4 acc[2];
    acc[0] = (f32x4){0.f, 0.f, 0.f, 0.f};
    acc[1] = (f32x4){0.f, 0.f, 0.f, 0.f};
    #pragma unroll
    for (int kt = 0; kt < 4; ++kt) {
        acc[0] = __builtin_amdgcn_mfma_f32_16x16x32_bf16(afrag[kt], bfrag[0][kt], acc[0], 0, 0, 0);
        acc[1] = __builtin_amdgcn_mfma_f32_16x16x32_bf16(afrag[kt], bfrag[1][kt], acc[1], 0, 0, 0);
    }

    float* o_s = (float*)a_s;
    #pragma unroll
    for (int nt = 0; nt < 2; ++nt) {
        const int d = nh * 32 + nt * 16 + m;
        #pragma unroll
        for (int r = 0; r < 4; ++r) {
            const int row = mt * 16 + quad * 4 + r;
            o_s[row * O_STRIDE + d] = acc[nt][r];
        }
    }
    __syncthreads();

    #pragma unroll
    for (int i = 0; i < 2; ++i) {
        const int idx = i * 512 + t;
        const int row = idx >> 4, c4 = (idx & 15) * 4;
        *(float4*)(out + (size_t)(pos0 + row) * 64 + c4) =
            *(const float4*)(o_s + row * O_STRIDE + c4);
    }
}

extern "C" void kernel_launch(void* const* d_in, const int* in_sizes, int n_in,
                              void* d_out, int out_size, void* d_ws, size_t ws_size,
                              hipStream_t stream) {
    const float* z      = (const float*)d_in[0];
    const int*   mask   = (const int*)d_in[1];
    const float* ln_w   = (const float*)d_in[2];
    const float* ln_b   = (const float*)d_in[3];
    const float* w_qkv  = (const float*)d_in[4];
    const float* w_bias = (const float*)d_in[5];
    const float* w_out  = (const float*)d_in[6];
    const float* w_gate = (const float*)d_in[7];
    float* out = (float*)d_out;

    char* ws = (char*)d_ws;
    __hip_bfloat16* qkv_ws  = (__hip_bfloat16*)(ws);
    float*          bias_ws = (float*)(ws + 50331648);
    __hip_bfloat16* h_ws    = (__hip_bfloat16*)(ws + 51380224);
    __hip_bfloat16* attn_bf = (__hip_bfloat16*)(ws + 59768832);

    k1_ln_proj_mfma<<<1024, 512, 0, stream>>>(z, ln_w, ln_b, w_qkv, w_bias,
                                              qkv_ws, h_ws, bias_ws);
    k2_attn_mfma<<<1024, 512, 0, stream>>>(qkv_ws, bias_ws, mask, attn_bf);
    k3_proj_mfma<<<1024, 512, 0, stream>>>(attn_bf, h_ws, w_gate, w_out, out);
}